// Round 1
// baseline (10594.599 us; speedup 1.0000x reference)
//
#include <hip/hip_runtime.h>

#define BB 256
#define SEQ 512
#define IDIM 32
#define HDIM 128
#define ODIM 64
#define NSUB 8

__device__ __forceinline__ float fast_tanh(float x) {
    // tanh(x) = 1 - 2/(1+exp(2x)); robust: x->+inf => 1, x->-inf => -1
    float e = __expf(2.0f * x);
    return 1.0f - 2.0f * __builtin_amdgcn_rcpf(1.0f + e);
}

// One block per batch element. 256 threads: thread (j, half), j = tid>>1 owns h[j],
// half = tid&1 owns half of W_h row j in registers. One barrier per ODE stage
// (double-buffered LDS broadcast of the stage argument).
__global__ __launch_bounds__(256) void lnn_recur(
    const float* __restrict__ x,
    const float* __restrict__ Wx,
    const float* __restrict__ Wh,
    const float* __restrict__ bias,
    const float* __restrict__ tau,
    float* __restrict__ hs)
{
    __shared__ float abuf[2][HDIM];
    const int b    = blockIdx.x;
    const int tid  = threadIdx.x;
    const int j    = tid >> 1;
    const int half = tid & 1;

    // W_h row-half into registers (64 VGPRs)
    float w[64];
    {
        const float4* wp = reinterpret_cast<const float4*>(Wh + j * HDIM + half * 64);
        #pragma unroll
        for (int kk = 0; kk < 16; ++kk) {
            float4 v = wp[kk];
            w[4*kk+0] = v.x; w[4*kk+1] = v.y; w[4*kk+2] = v.z; w[4*kk+3] = v.w;
        }
    }
    // W_x row-half into registers (16 VGPRs)
    float wxr[16];
    {
        const float4* wp = reinterpret_cast<const float4*>(Wx + j * IDIM + half * 16);
        #pragma unroll
        for (int m = 0; m < 4; ++m) {
            float4 v = wp[m];
            wxr[4*m+0] = v.x; wxr[4*m+1] = v.y; wxr[4*m+2] = v.z; wxr[4*m+3] = v.w;
        }
    }
    const float bj   = bias[j];
    const float itau = 1.0f / (fabsf(tau[j]) + 0.001f);
    const float DT   = 1.0f / (float)NSUB;

    float h  = 0.0f;
    int  par = 0;

    #pragma unroll 1
    for (int t = 0; t < SEQ; ++t) {
        // xp[j] = x_t . Wx_row_j  (split over halves, combined via shfl)
        float cbase;
        {
            const float4* xp4 = reinterpret_cast<const float4*>(x + ((size_t)b * SEQ + t) * IDIM + half * 16);
            float p0 = 0.f, p1 = 0.f;
            #pragma unroll
            for (int m = 0; m < 4; ++m) {
                float4 v = xp4[m];
                p0 += wxr[4*m+0] * v.x + wxr[4*m+2] * v.z;
                p1 += wxr[4*m+1] * v.y + wxr[4*m+3] * v.w;
            }
            float px = p0 + p1;
            px += __shfl_xor(px, 1);
            cbase = px + bj;
        }

        #pragma unroll 1
        for (int s = 0; s < NSUB; ++s) {
            float k1, k2, k3, k4, k5, k6;

            auto stage = [&](float a) -> float {
                if (half == 0) abuf[par][j] = a;   // both halves hold identical a
                __syncthreads();
                float a0 = 0.f, a1 = 0.f, a2 = 0.f, a3 = 0.f;
                const float4* ap = reinterpret_cast<const float4*>(&abuf[par][half * 64]);
                #pragma unroll
                for (int kk = 0; kk < 16; ++kk) {
                    float4 v = ap[kk];
                    a0 += w[4*kk+0] * v.x;
                    a1 += w[4*kk+1] * v.y;
                    a2 += w[4*kk+2] * v.z;
                    a3 += w[4*kk+3] * v.w;
                }
                float acc = (a0 + a1) + (a2 + a3);
                acc += __shfl_xor(acc, 1);         // full 128-dot in both halves
                par ^= 1;
                float th = fast_tanh(cbase + acc);
                return itau * (th - a);
            };

            k1 = stage(h);
            k2 = stage(h + DT * (0.2f * k1));
            k3 = stage(h + DT * (0.075f * k1 + 0.225f * k2));
            k4 = stage(h + DT * ((44.0f/45.0f) * k1 - (56.0f/15.0f) * k2 + (32.0f/9.0f) * k3));
            k5 = stage(h + DT * ((19372.0f/6561.0f) * k1 - (25360.0f/2187.0f) * k2
                               + (64448.0f/6561.0f) * k3 - (212.0f/729.0f) * k4));
            k6 = stage(h + DT * ((9017.0f/3168.0f) * k1 - (355.0f/33.0f) * k2
                               + (46732.0f/5247.0f) * k3 + (49.0f/176.0f) * k4
                               - (5103.0f/18656.0f) * k5));
            h = h + DT * ((35.0f/384.0f) * k1 + (500.0f/1113.0f) * k3 + (125.0f/192.0f) * k4
                        - (2187.0f/6784.0f) * k5 + (11.0f/84.0f) * k6);
        }

        if (half == 0) hs[((size_t)b * SEQ + t) * HDIM + j] = h;
    }
}

// outs[bt][o] = hs[bt] . Wout_row_o + bout[o]; trivially parallel, out of the hot loop.
__global__ __launch_bounds__(256) void lnn_out(
    const float* __restrict__ hs,
    const float* __restrict__ Wout,
    const float* __restrict__ bout,
    float* __restrict__ outs)
{
    __shared__ float wt[HDIM][ODIM + 1];   // transposed W_out, +1 pad
    const int tid = threadIdx.x;
    for (int i = tid; i < HDIM * ODIM; i += 256) {
        int o = i >> 7;     // i / HDIM
        int k = i & 127;    // i % HDIM
        wt[k][o] = Wout[i];
    }
    __syncthreads();

    const int o = tid & 63;
    const int r = tid >> 6;
    const float bo = bout[o];
    const int nbt = BB * SEQ;

    for (int bt = blockIdx.x * 4 + r; bt < nbt; bt += gridDim.x * 4) {
        const float4* hp = reinterpret_cast<const float4*>(hs + (size_t)bt * HDIM);
        float acc0 = bo, acc1 = 0.f, acc2 = 0.f, acc3 = 0.f;
        #pragma unroll
        for (int kk = 0; kk < 32; ++kk) {
            float4 v = hp[kk];
            acc0 += v.x * wt[4*kk+0][o];
            acc1 += v.y * wt[4*kk+1][o];
            acc2 += v.z * wt[4*kk+2][o];
            acc3 += v.w * wt[4*kk+3][o];
        }
        outs[(size_t)bt * ODIM + o] = (acc0 + acc1) + (acc2 + acc3);
    }
}

extern "C" void kernel_launch(void* const* d_in, const int* in_sizes, int n_in,
                              void* d_out, int out_size, void* d_ws, size_t ws_size,
                              hipStream_t stream) {
    const float* x    = (const float*)d_in[0];
    const float* Wx   = (const float*)d_in[1];
    const float* Wh   = (const float*)d_in[2];
    const float* bias = (const float*)d_in[3];
    const float* tau  = (const float*)d_in[4];
    const float* Wout = (const float*)d_in[5];
    const float* bout = (const float*)d_in[6];

    float* outs = (float*)d_out;
    float* hs   = outs + (size_t)BB * SEQ * ODIM;

    lnn_recur<<<BB, 256, 0, stream>>>(x, Wx, Wh, bias, tau, hs);
    lnn_out<<<2048, 256, 0, stream>>>(hs, Wout, bout, outs);
}

// Round 2
// 7778.156 us; speedup vs baseline: 1.3621x; 1.3621x over previous
//
#include <hip/hip_runtime.h>

#define BB 256
#define SEQ 512
#define IDIM 32
#define HDIM 128
#define ODIM 64
#define NSUB 8

typedef float v2f __attribute__((ext_vector_type(2)));

__device__ __forceinline__ float dpp_xor1_add(float x) {
    // pairwise (lane ^ 1) exchange via DPP quad_perm [1,0,3,2] — VALU latency, no LDS
    int yi = __builtin_amdgcn_mov_dpp(__float_as_int(x), 0xB1, 0xF, 0xF, false);
    return x + __int_as_float(yi);
}

// One block per batch element. 256 threads: thread (j, half); j = tid>>1 owns h[j],
// half = tid&1 owns half of W_h row j in registers (as float2 -> v_pk_fma_f32).
// One __syncthreads per ODE stage (double-buffered padded LDS broadcast).
__global__ __launch_bounds__(256) void lnn_recur(
    const float* __restrict__ x,
    const float* __restrict__ Wx,
    const float* __restrict__ Wh,
    const float* __restrict__ bias,
    const float* __restrict__ tau,
    float* __restrict__ hs)
{
    // half=0 data at [0..63], half=1 data at [72..135]: +8 float skew => disjoint banks
    __shared__ float abuf[2][144];
    const int b    = blockIdx.x;
    const int tid  = threadIdx.x;
    const int j    = tid >> 1;
    const int half = tid & 1;
    const int jw   = j + ((j >> 6) << 3);   // skewed write index

    // W_h row-half into registers as 32 float2 (64 VGPRs)
    v2f w2[32];
    {
        const float4* wp = reinterpret_cast<const float4*>(Wh + j * HDIM + half * 64);
        #pragma unroll
        for (int kk = 0; kk < 16; ++kk) {
            float4 v = wp[kk];
            w2[2*kk+0] = v2f{v.x, v.y};
            w2[2*kk+1] = v2f{v.z, v.w};
        }
    }
    // W_x row-half into registers as 8 float2
    v2f wx2[8];
    {
        const float4* wp = reinterpret_cast<const float4*>(Wx + j * IDIM + half * 16);
        #pragma unroll
        for (int m = 0; m < 4; ++m) {
            float4 v = wp[m];
            wx2[2*m+0] = v2f{v.x, v.y};
            wx2[2*m+1] = v2f{v.z, v.w};
        }
    }
    const float bj   = bias[j];
    const float itau = 1.0f / (fabsf(tau[j]) + 0.001f);
    const float DT   = 1.0f / (float)NSUB;
    const float dti  = DT * itau;           // fold dt into stage outputs
    const float K2E  = 2.885390081777927f;  // 2*log2(e): tanh(z)=1-2/(1+exp2(z*K2E))

    float h  = 0.0f;
    int  par = 0;

    #pragma unroll 1
    for (int t = 0; t < SEQ; ++t) {
        // cbase[j] = x_t . Wx_row_j + bias_j
        float cbase;
        {
            const float4* xp4 = reinterpret_cast<const float4*>(x + ((size_t)b * SEQ + t) * IDIM + half * 16);
            v2f p0 = v2f{0.f, 0.f}, p1 = v2f{0.f, 0.f};
            #pragma unroll
            for (int m = 0; m < 4; ++m) {
                float4 v = xp4[m];
                p0 += wx2[2*m+0] * v2f{v.x, v.y};
                p1 += wx2[2*m+1] * v2f{v.z, v.w};
            }
            v2f ps = p0 + p1;
            cbase = dpp_xor1_add(ps.x + ps.y) + bj;
        }

        #pragma unroll 1
        for (int s = 0; s < NSUB; ++s) {
            float m1, m2, m3, m4, m5, m6;

            // returns m = dt * k = dti * (tanh(cbase + Wh.a) - a)
            auto stage = [&](float a) -> float {
                if (half == 0) abuf[par][jw] = a;
                __syncthreads();
                const float4* ap = reinterpret_cast<const float4*>(&abuf[par][half * 72]);
                v2f acc0 = v2f{0.f, 0.f}, acc1 = v2f{0.f, 0.f};
                v2f acc2 = v2f{0.f, 0.f}, acc3 = v2f{0.f, 0.f};
                #pragma unroll
                for (int kk = 0; kk < 8; ++kk) {
                    float4 va = ap[2*kk+0];
                    float4 vb = ap[2*kk+1];
                    acc0 += w2[4*kk+0] * v2f{va.x, va.y};
                    acc1 += w2[4*kk+1] * v2f{va.z, va.w};
                    acc2 += w2[4*kk+2] * v2f{vb.x, vb.y};
                    acc3 += w2[4*kk+3] * v2f{vb.z, vb.w};
                }
                v2f r = (acc0 + acc1) + (acc2 + acc3);
                par ^= 1;
                float dot = dpp_xor1_add(r.x + r.y);
                float z   = cbase + dot;
                float e   = exp2f(z * K2E);
                float th  = 1.0f - 2.0f * __builtin_amdgcn_rcpf(1.0f + e);
                return dti * (th - a);
            };

            m1 = stage(h);
            m2 = stage(h + 0.2f * m1);
            m3 = stage(h + (0.075f * m1 + 0.225f * m2));
            m4 = stage(h + ((44.0f/45.0f) * m1 - (56.0f/15.0f) * m2) + (32.0f/9.0f) * m3);
            m5 = stage(h + ((19372.0f/6561.0f) * m1 - (25360.0f/2187.0f) * m2)
                         + ((64448.0f/6561.0f) * m3 - (212.0f/729.0f) * m4));
            m6 = stage(h + ((9017.0f/3168.0f) * m1 - (355.0f/33.0f) * m2)
                         + ((46732.0f/5247.0f) * m3 + (49.0f/176.0f) * m4)
                         - (5103.0f/18656.0f) * m5);
            h = h + (((35.0f/384.0f) * m1 + (500.0f/1113.0f) * m3)
                   + ((125.0f/192.0f) * m4 - (2187.0f/6784.0f) * m5))
                  + (11.0f/84.0f) * m6;
        }

        if (half == 0) hs[((size_t)b * SEQ + t) * HDIM + j] = h;
    }
}

// outs[bt][o] = hs[bt] . Wout_row_o + bout[o]; trivially parallel, out of the hot loop.
__global__ __launch_bounds__(256) void lnn_out(
    const float* __restrict__ hs,
    const float* __restrict__ Wout,
    const float* __restrict__ bout,
    float* __restrict__ outs)
{
    __shared__ float wt[HDIM][ODIM + 1];
    const int tid = threadIdx.x;
    for (int i = tid; i < HDIM * ODIM; i += 256) {
        int o = i >> 7;
        int k = i & 127;
        wt[k][o] = Wout[i];
    }
    __syncthreads();

    const int o = tid & 63;
    const int r = tid >> 6;
    const float bo = bout[o];
    const int nbt = BB * SEQ;

    for (int bt = blockIdx.x * 4 + r; bt < nbt; bt += gridDim.x * 4) {
        const float4* hp = reinterpret_cast<const float4*>(hs + (size_t)bt * HDIM);
        float acc0 = bo, acc1 = 0.f, acc2 = 0.f, acc3 = 0.f;
        #pragma unroll
        for (int kk = 0; kk < 32; ++kk) {
            float4 v = hp[kk];
            acc0 += v.x * wt[4*kk+0][o];
            acc1 += v.y * wt[4*kk+1][o];
            acc2 += v.z * wt[4*kk+2][o];
            acc3 += v.w * wt[4*kk+3][o];
        }
        outs[(size_t)bt * ODIM + o] = (acc0 + acc1) + (acc2 + acc3);
    }
}

extern "C" void kernel_launch(void* const* d_in, const int* in_sizes, int n_in,
                              void* d_out, int out_size, void* d_ws, size_t ws_size,
                              hipStream_t stream) {
    const float* x    = (const float*)d_in[0];
    const float* Wx   = (const float*)d_in[1];
    const float* Wh   = (const float*)d_in[2];
    const float* bias = (const float*)d_in[3];
    const float* tau  = (const float*)d_in[4];
    const float* Wout = (const float*)d_in[5];
    const float* bout = (const float*)d_in[6];

    float* outs = (float*)d_out;
    float* hs   = outs + (size_t)BB * SEQ * ODIM;

    lnn_recur<<<BB, 256, 0, stream>>>(x, Wx, Wh, bias, tau, hs);
    lnn_out<<<2048, 256, 0, stream>>>(hs, Wout, bout, outs);
}